// Round 15
// baseline (459.496 us; speedup 1.0000x reference)
//
#include <hip/hip_runtime.h>
#include <hip/hip_bf16.h>
#include <hip/hip_fp16.h>
#include <hip/hip_cooperative_groups.h>

namespace cg = cooperative_groups;

// GCN 2-layer: h1 = relu(A_hat (x@W1) + b1); out = log_softmax(A_hat (h1@W2) + b2)
// R15: cooperative fusion, occupancy-correct: 512-thread blocks (8 waves),
// __launch_bounds__(512,8) -> VGPR<=64 -> 4 blocks/CU = 32 waves/CU. LDS
// 39936 B/block (4x40KB fits 160KB). ALL phases grid-strided; grid size chosen
// at launch from hipOccupancyMaxActiveBlocksPerMultiprocessor (graceful degrade
// instead of R14's failed-launch). Phase bodies = R12.

#define F1 64
#define F2 16
#define NBKT 256  // scatter histogram bins (nb = 196)
#define BSH 512   // nodes per bucket; bucket = dst>>9, local = dst&511
#define NSB 512   // scatter work units == segments per bucket
#define BDIM 512
#define STG 8960  // stage capacity (mean 8192, sigma ~90 -> +8.5 sigma)

typedef _Float16 f16x8 __attribute__((ext_vector_type(8)));
typedef _Float16 f16x4 __attribute__((ext_vector_type(4)));
typedef _Float16 f16x2 __attribute__((ext_vector_type(2)));
typedef float f32x4 __attribute__((ext_vector_type(4)));

__device__ inline f16x8 shfl_xor_f16x8(f16x8 v, int off) {
  union U { f16x8 h; int i[4]; } a, b;
  a.h = v;
#pragma unroll
  for (int k = 0; k < 4; ++k) b.i[k] = __shfl_xor(a.i[k], off);
  return b.h;
}
__device__ inline f16x4 shfl_xor_f16x4(f16x4 v, int off) {
  union U { f16x4 h; int i[2]; } a, b;
  a.h = v;
#pragma unroll
  for (int k = 0; k < 2; ++k) b.i[k] = __shfl_xor(a.i[k], off);
  return b.h;
}

__global__ void __launch_bounds__(BDIM, 8) k_fused(
    const int* __restrict__ src, const int* __restrict__ dst,
    const float* __restrict__ x, const float* __restrict__ W1,
    const float* __restrict__ b1, const float* __restrict__ W2,
    const float* __restrict__ b2, int* __restrict__ tmp,
    int* __restrict__ segstart, int* __restrict__ csr,
    int* __restrict__ rowptr, float* __restrict__ dis,
    __half* __restrict__ W1T, __half* __restrict__ W2T,
    __half* __restrict__ h1, __half* __restrict__ h2,
    float* __restrict__ out, int N, int E, int nb, int chunk) {
  cg::grid_group grid = cg::this_grid();
  __shared__ int sStage[STG];
  __shared__ int sA[BSH];
  __shared__ int sB[BSH];
  int t = threadIdx.x, sb = blockIdx.x;
  int nblk = gridDim.x;

  // ===== Phase 0: scatter (grid-strided over NSB chunks) + W transpose =====
  if (sb == nblk - 1) {  // transpose on the last block (idle or least-loaded)
    for (int i = t; i < 64 * 64; i += BDIM) {
      int n = i >> 6, k = i & 63;
      W1T[i] = __float2half(W1[k * 64 + n]);
    }
    for (int i = t; i < 16 * 64; i += BDIM) {
      int n = i >> 6, k = i & 63;
      W2T[i] = __float2half(W2[k * 16 + n]);
    }
  }
  for (int u = sb; u < NSB; u += nblk) {
    __syncthreads();  // protect sA/sB reuse across iterations
    int beg = u * chunk, end = min(beg + chunk, E);
    for (int i = t; i < NBKT; i += BDIM) sA[i] = 0;  // hist
    __syncthreads();
    int e;
    for (e = beg + t * 4; e + 4 <= end; e += 4 * BDIM) {
      int4 d4 = *(const int4*)(dst + e);
      atomicAdd(&sA[d4.x >> 9], 1);
      atomicAdd(&sA[d4.y >> 9], 1);
      atomicAdd(&sA[d4.z >> 9], 1);
      atomicAdd(&sA[d4.w >> 9], 1);
    }
    for (; e < end; ++e) atomicAdd(&sA[dst[e] >> 9], 1);
    __syncthreads();
    // exclusive scan of 256 bins: scan in sB, cursors into sA
    if (t < NBKT) sB[t] = sA[t];
    __syncthreads();
    for (int off = 1; off < NBKT; off <<= 1) {
      int a = (t < NBKT && t >= off) ? sB[t - off] : 0;
      __syncthreads();
      if (t < NBKT) sB[t] += a;
      __syncthreads();
    }
    if (t < NBKT) sA[t] = (t == 0) ? 0 : sB[t - 1];  // cursor
    __syncthreads();
    for (int i = t; i < nb; i += BDIM) segstart[u * (nb + 1) + i] = beg + sA[i];
    if (t == 0) segstart[u * (nb + 1) + nb] = end;
    __syncthreads();
    // place packed edges densely in [beg, end)
    for (e = beg + t * 4; e + 4 <= end; e += 4 * BDIM) {
      int4 d4 = *(const int4*)(dst + e);
      int4 s4 = *(const int4*)(src + e);
      int b, off;
      b = d4.x >> 9; off = atomicAdd(&sA[b], 1); tmp[beg + off] = (s4.x << 9) | (d4.x & 511);
      b = d4.y >> 9; off = atomicAdd(&sA[b], 1); tmp[beg + off] = (s4.y << 9) | (d4.y & 511);
      b = d4.z >> 9; off = atomicAdd(&sA[b], 1); tmp[beg + off] = (s4.z << 9) | (d4.z & 511);
      b = d4.w >> 9; off = atomicAdd(&sA[b], 1); tmp[beg + off] = (s4.w << 9) | (d4.w & 511);
    }
    for (; e < end; ++e) {
      int d = dst[e];
      int b = d >> 9;
      int off = atomicAdd(&sA[b], 1);
      tmp[beg + off] = (src[e] << 9) | (d & 511);
    }
  }
  grid.sync();

  // ===== Phase 1: per-bucket LDS-staged sort -> csr/rowptr/dis (strided) ====
  for (int b = sb; b < nb; b += nblk) {
    __syncthreads();  // protect reuse across iterations
    // thread t owns scatter-unit t's segment for bucket b (NSB == BDIM)
    int s0 = segstart[t * (nb + 1) + b];
    int len = segstart[t * (nb + 1) + b + 1] - s0;
    // bbase[b] = sum_t (s0 - t*chunk)
    sA[t] = s0 - t * chunk;
    __syncthreads();
    for (int off = BDIM / 2; off > 0; off >>= 1) {
      if (t < off) sA[t] += sA[t + off];
      __syncthreads();
    }
    int beg = sA[0];
    __syncthreads();
    // inclusive scan of segment lengths -> stage offsets
    sB[t] = len;
    __syncthreads();
    for (int off = 1; off < BDIM; off <<= 1) {
      int a = (t >= off) ? sB[t - off] : 0;
      __syncthreads();
      sB[t] += a;
      __syncthreads();
    }
    int total = sB[BDIM - 1];
    int my0 = (t == 0) ? 0 : sB[t - 1];
    // stage own segment (single global read of tmp)
    for (int i = 0; i < len; ++i) sStage[my0 + i] = tmp[s0 + i];
    sA[t] = 0;  // counts
    __syncthreads();
    for (int i = t; i < total; i += BDIM) atomicAdd(&sA[sStage[i] & (BSH - 1)], 1);
    __syncthreads();
    int cntv = sA[t];
    // inclusive scan of counts in sB
    sB[t] = cntv;
    __syncthreads();
    for (int off = 1; off < BDIM; off <<= 1) {
      int a = (t >= off) ? sB[t - off] : 0;
      __syncthreads();
      sB[t] += a;
      __syncthreads();
    }
    int excl = (t == 0) ? 0 : sB[t - 1];
    int n = b * BSH + t;
    if (n <= N) rowptr[n] = beg + excl;  // n==N lands on E
    if (n < N) dis[n] = rsqrtf((float)(cntv + 1));
    __syncthreads();     // all excl reads of sB done
    sB[t] = excl;        // lofs
    sA[t] = 0;           // cursor
    __syncthreads();
    for (int i = t; i < total; i += BDIM) {
      int p = sStage[i];
      int l = p & (BSH - 1);
      int off = atomicAdd(&sA[l], 1);
      csr[beg + sB[l] + off] = p >> 9;
    }
  }
  grid.sync();

  // ===== Phase 2: MFMA GEMM1, h1[n] = fp16(dis[n]*(x[n]@W1)) ================
  {
    int wv = t >> 6, lane = t & 63;
    int m = lane & 15, q = lane >> 4;
    const _Float16* wt = (const _Float16*)W1T;
    for (int base = sb * 128; base < N; base += nblk * 128) {
      int row0 = base + wv * 16;
      int arow = min(row0 + m, N - 1);
      f16x8 a[2];
#pragma unroll
      for (int kt = 0; kt < 2; ++kt) {
        const float4* xp = (const float4*)(x + (size_t)arow * 64 + kt * 32 + q * 8);
        float4 u = xp[0], v = xp[1];
        a[kt][0] = (_Float16)u.x; a[kt][1] = (_Float16)u.y;
        a[kt][2] = (_Float16)u.z; a[kt][3] = (_Float16)u.w;
        a[kt][4] = (_Float16)v.x; a[kt][5] = (_Float16)v.y;
        a[kt][6] = (_Float16)v.z; a[kt][7] = (_Float16)v.w;
      }
      f32x4 acc[4] = {};
#pragma unroll
      for (int c = 0; c < 4; ++c) {  // load B per column: 2 live frags, fits VGPR cap
        f16x8 b0 = *(const f16x8*)&wt[(c * 16 + m) * 64 + 0 * 32 + q * 8];
        f16x8 b1 = *(const f16x8*)&wt[(c * 16 + m) * 64 + 1 * 32 + q * 8];
        acc[c] = __builtin_amdgcn_mfma_f32_16x16x32_f16(a[0], b0, acc[c], 0, 0, 0);
        acc[c] = __builtin_amdgcn_mfma_f32_16x16x32_f16(a[1], b1, acc[c], 0, 0, 0);
      }
#pragma unroll
      for (int r = 0; r < 4; ++r) {
        int n = row0 + q * 4 + r;
        if (n < N) {
          float dn = dis[n];
#pragma unroll
          for (int c = 0; c < 4; ++c)
            h1[(size_t)n * 64 + c * 16 + m] = __float2half(acc[c][r] * dn);
        }
      }
    }
  }
  grid.sync();

  // ===== Phase 3: agg1 + fused GEMM2 (2 nodes/wave) =========================
  {
    int wv = t >> 6, lane = t & 63;
    int half = lane >> 5;
    int sub = (lane >> 3) & 3;
    int fl = lane & 7;
    const _Float16* hp = (const _Float16*)h1;
    const _Float16* wt = (const _Float16*)W2T;
    float4 bu = *(const float4*)(b1 + fl * 8);
    float4 bv = *(const float4*)(b1 + fl * 8 + 4);
    f16x8 wj[4];
#pragma unroll
    for (int i = 0; i < 4; ++i)
      wj[i] = *(const f16x8*)&wt[(sub * 4 + i) * 64 + fl * 8];
    for (int w = sb * 8 + wv; w * 2 < N; w += nblk * 8) {
      int n = w * 2 + half;
      if (n < N) {
        float dn = dis[n];
        f16x8 acc0 = {}, acc1 = {};
        if (sub == 0)
          acc0 = *(const f16x8*)&hp[(size_t)n * 64 + fl * 8];
        int beg = rowptr[n], end = rowptr[n + 1];
        int e = beg + sub;
        int sA2 = (e < end) ? csr[e] : -1;
        int sB2 = (e + 4 < end) ? csr[e + 4] : -1;
        while (sB2 >= 0) {
          int e2 = e + 8;
          int sC2 = (e2 < end) ? csr[e2] : -1;
          int sD2 = (e2 + 4 < end) ? csr[e2 + 4] : -1;
          f16x8 v0 = *(const f16x8*)&hp[(size_t)sA2 * 64 + fl * 8];
          f16x8 v1 = *(const f16x8*)&hp[(size_t)sB2 * 64 + fl * 8];
          acc0 += v0;
          acc1 += v1;
          sA2 = sC2; sB2 = sD2; e = e2;
        }
        if (sA2 >= 0)
          acc0 += *(const f16x8*)&hp[(size_t)sA2 * 64 + fl * 8];
        f16x8 acc = acc0 + acc1;
        acc += shfl_xor_f16x8(acc, 8);
        acc += shfl_xor_f16x8(acc, 16);
        float bb[8] = {bu.x, bu.y, bu.z, bu.w, bv.x, bv.y, bv.z, bv.w};
        f16x8 hr16;
#pragma unroll
        for (int k = 0; k < 8; ++k)
          hr16[k] = (_Float16)fmaxf(fmaf(dn, (float)acc[k], bb[k]), 0.f);
        const f16x2* h2v = (const f16x2*)&hr16;
        float p[4];
#pragma unroll
        for (int i = 0; i < 4; ++i) {
          const f16x2* wv2 = (const f16x2*)&wj[i];
          f16x2 qq = {};
#pragma unroll
          for (int k = 0; k < 4; ++k) qq += h2v[k] * wv2[k];
          float pi = (float)qq[0] + (float)qq[1];
          pi += __shfl_xor(pi, 1);
          pi += __shfl_xor(pi, 2);
          pi += __shfl_xor(pi, 4);
          p[i] = pi;
        }
        if (fl == 0) {
          f16x4 o;
#pragma unroll
          for (int i = 0; i < 4; ++i) o[i] = (_Float16)(p[i] * dn);
          *(f16x4*)((_Float16*)h2 + (size_t)n * 16 + sub * 4) = o;
        }
      }
    }
  }
  grid.sync();

  // ===== Phase 4: agg2 + bias + log_softmax (2 nodes/wave) ==================
  {
    int wv = t >> 6, lane = t & 63;
    int half = lane >> 5;
    int sub = (lane >> 2) & 7;
    int fl = lane & 3;
    const _Float16* hp = (const _Float16*)h2;
    for (int w = sb * 8 + wv; w * 2 < N; w += nblk * 8) {
      int n = w * 2 + half;
      if (n < N) {
        f16x4 acc0 = {}, acc1 = {};
        if (sub == 0)
          acc0 = *(const f16x4*)&hp[(size_t)n * 16 + fl * 4];
        int beg = rowptr[n], end = rowptr[n + 1];
        int e = beg + sub;
        int sA2 = (e < end) ? csr[e] : -1;
        int sB2 = (e + 8 < end) ? csr[e + 8] : -1;
        while (sB2 >= 0) {
          int e2 = e + 16;
          int sC2 = (e2 < end) ? csr[e2] : -1;
          int sD2 = (e2 + 8 < end) ? csr[e2 + 8] : -1;
          f16x4 v0 = *(const f16x4*)&hp[(size_t)sA2 * 16 + fl * 4];
          f16x4 v1 = *(const f16x4*)&hp[(size_t)sB2 * 16 + fl * 4];
          acc0 += v0;
          acc1 += v1;
          sA2 = sC2; sB2 = sD2; e = e2;
        }
        if (sA2 >= 0)
          acc0 += *(const f16x4*)&hp[(size_t)sA2 * 16 + fl * 4];
        f16x4 acc = acc0 + acc1;
        acc += shfl_xor_f16x4(acc, 4);
        acc += shfl_xor_f16x4(acc, 8);
        acc += shfl_xor_f16x4(acc, 16);
        if (sub == 0) {
          float dn = dis[n];
          float4 bb = *(const float4*)(b2 + fl * 4);
          float v0 = fmaf(dn, (float)acc[0], bb.x);
          float v1 = fmaf(dn, (float)acc[1], bb.y);
          float v2 = fmaf(dn, (float)acc[2], bb.z);
          float v3 = fmaf(dn, (float)acc[3], bb.w);
          float m = fmaxf(fmaxf(v0, v1), fmaxf(v2, v3));
          m = fmaxf(m, __shfl_xor(m, 1));
          m = fmaxf(m, __shfl_xor(m, 2));
          float s2 = __expf(v0 - m) + __expf(v1 - m) + __expf(v2 - m) + __expf(v3 - m);
          s2 += __shfl_xor(s2, 1);
          s2 += __shfl_xor(s2, 2);
          float ls = m + __logf(s2);
          float4 o = {v0 - ls, v1 - ls, v2 - ls, v3 - ls};
          *(float4*)(out + (size_t)n * 16 + fl * 4) = o;
        }
      }
    }
  }
}

extern "C" void kernel_launch(void* const* d_in, const int* in_sizes, int n_in,
                              void* d_out, int out_size, void* d_ws, size_t ws_size,
                              hipStream_t stream) {
  const float* x = (const float*)d_in[0];
  const int* ei = (const int*)d_in[1];
  const float* W1 = (const float*)d_in[2];
  const float* b1 = (const float*)d_in[3];
  const float* W2 = (const float*)d_in[4];
  const float* b2 = (const float*)d_in[5];
  float* out = (float*)d_out;

  int N = in_sizes[0] / F1;  // 100000
  int E = in_sizes[1] / 2;   // 1600000
  const int* src = ei;
  const int* dst = ei + E;
  int nb = (N + BSH - 1) >> 9;  // 196 buckets
  int chunk = ((E + NSB - 1) / NSB + 3) & ~3;  // 3128

  char* ws = (char*)d_ws;
  size_t o_w1t   = 0;                                        // 64*64 fp16
  size_t o_w2t   = o_w1t + 64 * 64 * 2;                      // 16*64 fp16
  size_t o_seg   = (o_w2t + 16 * 64 * 2 + 255) & ~(size_t)255;          // NSB*(nb+1) int
  size_t o_dis   = (o_seg + (size_t)NSB * (nb + 1) * 4 + 255) & ~(size_t)255;  // N f32
  size_t o_rowp  = (o_dis + (size_t)N * 4 + 255) & ~(size_t)255;        // N+1 int
  size_t o_tmp   = (o_rowp + (size_t)(N + 1) * 4 + 255) & ~(size_t)255; // NSB*chunk int
  size_t o_csr   = (o_tmp + (size_t)NSB * chunk * 4 + 255) & ~(size_t)255;  // E int
  size_t o_h1    = (o_csr + (size_t)E * 4 + 255) & ~(size_t)255;        // N*64 fp16
  size_t o_h2    = (o_h1 + (size_t)N * 64 * 2 + 255) & ~(size_t)255;    // N*16 fp16

  __half* W1T  = (__half*)(ws + o_w1t);
  __half* W2T  = (__half*)(ws + o_w2t);
  int* segst   = (int*)(ws + o_seg);
  float* dis   = (float*)(ws + o_dis);
  int* rowptr  = (int*)(ws + o_rowp);
  int* tmp     = (int*)(ws + o_tmp);
  int* csr     = (int*)(ws + o_csr);
  __half* h1   = (__half*)(ws + o_h1);
  __half* h2   = (__half*)(ws + o_h2);

  // pick the largest co-residable grid (4 blocks/CU target); any size is correct
  int maxb = 0;
  hipOccupancyMaxActiveBlocksPerMultiprocessor(&maxb, (const void*)k_fused, BDIM, 0);
  if (maxb < 1) maxb = 1;
  if (maxb > 4) maxb = 4;
  int nblk = 256 * maxb;

  void* args[] = {&src, &dst, &x, &W1, &b1, &W2, &b2, &tmp, &segst, &csr,
                  &rowptr, &dis, &W1T, &W2T, &h1, &h2, &out, &N, &E, &nb, &chunk};
  hipLaunchCooperativeKernel((void*)k_fused, dim3(nblk), dim3(BDIM), args, 0, stream);
}

// Round 16
// 174.662 us; speedup vs baseline: 2.6308x; 2.6308x over previous
//
#include <hip/hip_runtime.h>
#include <hip/hip_bf16.h>
#include <hip/hip_fp16.h>

// GCN 2-layer: h1 = relu(A_hat (x@W1) + b1); out = log_softmax(A_hat (h1@W2) + b2)
// R16 = R12 revert (best verified: 173 µs). 5 dispatches: scatter(+Wtranspose)
// -> LDS-staged csr (bbase derived from segstart) -> MFMA gemm1 -> fused
// agg1+gemm2 (2 nodes/wave) -> agg2+log_softmax (2 nodes/wave).
// Fusion attempts R13-R15 bracketed: 1 blk/CU = latency 2x; VGPR-capped
// full-occupancy = scratch spills 6x. Multi-kernel per-phase tuning wins.

#define F1 64
#define F2 16
#define NBKT 256  // bucket array size (nb = 196)
#define BSH 512   // nodes per bucket; bucket = dst>>9, local = dst&511
#define NSB 256   // scatter blocks (== segments per bucket)
#define SBD 1024  // scatter block dim
#define STG 9216  // stage capacity (mean 8163, sigma ~90)

typedef _Float16 f16x8 __attribute__((ext_vector_type(8)));
typedef _Float16 f16x4 __attribute__((ext_vector_type(4)));
typedef _Float16 f16x2 __attribute__((ext_vector_type(2)));
typedef float f32x4 __attribute__((ext_vector_type(4)));

__device__ inline f16x8 shfl_xor_f16x8(f16x8 v, int off) {
  union U { f16x8 h; int i[4]; } a, b;
  a.h = v;
#pragma unroll
  for (int k = 0; k < 4; ++k) b.i[k] = __shfl_xor(a.i[k], off);
  return b.h;
}
__device__ inline f16x4 shfl_xor_f16x4(f16x4 v, int off) {
  union U { f16x4 h; int i[2]; } a, b;
  a.h = v;
#pragma unroll
  for (int k = 0; k < 2; ++k) b.i[k] = __shfl_xor(a.i[k], off);
  return b.h;
}

// ---- 1) per-block local counting sort into block-major tmp + segstart ----
// Extra block (blockIdx == NSB) does the fp16 weight transpose instead.
__global__ void k_scatterL(const int* __restrict__ src, const int* __restrict__ dst,
                           int* __restrict__ tmp, int* __restrict__ segstart,
                           int E, int nb, int chunk,
                           const float* __restrict__ W1, const float* __restrict__ W2,
                           __half* __restrict__ W1T, __half* __restrict__ W2T) {
  int t = threadIdx.x, sb = blockIdx.x;
  if (sb == NSB) {  // weight transpose block
    for (int i = t; i < 64 * 64; i += SBD) {
      int n = i >> 6, k = i & 63;
      W1T[i] = __float2half(W1[k * 64 + n]);
    }
    for (int i = t; i < 16 * 64; i += SBD) {
      int n = i >> 6, k = i & 63;
      W2T[i] = __float2half(W2[k * 16 + n]);
    }
    return;
  }
  __shared__ int h[NBKT];
  __shared__ int cur[NBKT];
  __shared__ int sc[NBKT];
  int beg = sb * chunk, end = min(beg + chunk, E);
  for (int i = t; i < NBKT; i += SBD) h[i] = 0;
  __syncthreads();
  int e;
  for (e = beg + t * 4; e + 4 <= end; e += 4 * SBD) {
    int4 d4 = *(const int4*)(dst + e);
    atomicAdd(&h[d4.x >> 9], 1);
    atomicAdd(&h[d4.y >> 9], 1);
    atomicAdd(&h[d4.z >> 9], 1);
    atomicAdd(&h[d4.w >> 9], 1);
  }
  for (; e < end; ++e) atomicAdd(&h[dst[e] >> 9], 1);
  __syncthreads();
  // exclusive scan of 256 bins (first 256 threads own 1 bin each)
  if (t < NBKT) sc[t] = h[t];
  __syncthreads();
  for (int off = 1; off < NBKT; off <<= 1) {
    int a = (t < NBKT && t >= off) ? sc[t - off] : 0;
    __syncthreads();
    if (t < NBKT) sc[t] += a;
    __syncthreads();
  }
  if (t < NBKT) cur[t] = (t == 0) ? 0 : sc[t - 1];
  __syncthreads();
  for (int i = t; i < nb; i += SBD) segstart[sb * (nb + 1) + i] = beg + cur[i];
  if (t == 0) segstart[sb * (nb + 1) + nb] = end;
  __syncthreads();
  // pass 2: place packed edges densely in [beg, end)
  for (e = beg + t * 4; e + 4 <= end; e += 4 * SBD) {
    int4 d4 = *(const int4*)(dst + e);
    int4 s4 = *(const int4*)(src + e);
    int b, off;
    b = d4.x >> 9; off = atomicAdd(&cur[b], 1); tmp[beg + off] = (s4.x << 9) | (d4.x & 511);
    b = d4.y >> 9; off = atomicAdd(&cur[b], 1); tmp[beg + off] = (s4.y << 9) | (d4.y & 511);
    b = d4.z >> 9; off = atomicAdd(&cur[b], 1); tmp[beg + off] = (s4.z << 9) | (d4.z & 511);
    b = d4.w >> 9; off = atomicAdd(&cur[b], 1); tmp[beg + off] = (s4.w << 9) | (d4.w & 511);
  }
  for (; e < end; ++e) {
    int d = dst[e];
    int b = d >> 9;
    int off = atomicAdd(&cur[b], 1);
    tmp[beg + off] = (src[e] << 9) | (d & 511);
  }
}

// ---- 2) per-bucket single-pass LDS-staged sort -> csr + rowptr + dis ----
// bbase[b] = sum_t (segstart[t][b] - t*chunk)  (no bcnt array, no memset)
__global__ void k_csr(const int* __restrict__ tmp, const int* __restrict__ segstart,
                      int* __restrict__ csr, int* __restrict__ rowptr,
                      float* __restrict__ dis, int N, int nb, int chunk) {
  __shared__ int stage[STG];
  __shared__ int sc[BSH];
  __shared__ int cnt[BSH];
  __shared__ int lofs[BSH];
  __shared__ int s_beg;
  int b = blockIdx.x, t = threadIdx.x;  // 512 threads
  // segment of scatter-block t (t < NSB)
  int s0 = 0, len = 0;
  if (t < NSB) {
    s0 = segstart[t * (nb + 1) + b];
    len = segstart[t * (nb + 1) + b + 1] - s0;
  }
  // bbase reduction: sum over t of (s0 - t*chunk)
  sc[t] = (t < NSB) ? (s0 - t * chunk) : 0;
  __syncthreads();
  for (int off = BSH / 2; off > 0; off >>= 1) {
    if (t < off) sc[t] += sc[t + off];
    __syncthreads();
  }
  if (t == 0) s_beg = sc[0];
  __syncthreads();
  int beg = s_beg;
  // seg-length scan for stage offsets
  sc[t] = (t < NSB) ? len : 0;
  __syncthreads();
  for (int off = 1; off < NSB; off <<= 1) {
    int a = (t < NSB && t >= off) ? sc[t - off] : 0;
    __syncthreads();
    if (t < NSB) sc[t] += a;
    __syncthreads();
  }
  int total = sc[NSB - 1];
  int my0 = (t == 0) ? 0 : ((t < NSB) ? sc[t - 1] : 0);
  // stage this bucket's edges into LDS (single global read of tmp)
  if (t < NSB) {
    int i = 0;
    for (; i + 4 <= len; i += 4) {
      int v0 = tmp[s0 + i], v1 = tmp[s0 + i + 1], v2 = tmp[s0 + i + 2], v3 = tmp[s0 + i + 3];
      stage[my0 + i] = v0; stage[my0 + i + 1] = v1;
      stage[my0 + i + 2] = v2; stage[my0 + i + 3] = v3;
    }
    for (; i < len; ++i) stage[my0 + i] = tmp[s0 + i];
  }
  cnt[t] = 0;
  __syncthreads();
  for (int i = t; i < total; i += BSH) atomicAdd(&cnt[stage[i] & (BSH - 1)], 1);
  __syncthreads();
  sc[t] = cnt[t];
  __syncthreads();
  for (int off = 1; off < BSH; off <<= 1) {
    int a = (t >= off) ? sc[t - off] : 0;
    __syncthreads();
    sc[t] += a;
    __syncthreads();
  }
  int excl = (t == 0) ? 0 : sc[t - 1];
  lofs[t] = excl;
  int n = b * BSH + t;
  if (n <= N) rowptr[n] = beg + excl;  // n==N lands on E
  if (n < N) dis[n] = rsqrtf((float)(cnt[t] + 1));
  cnt[t] = 0;  // reuse as cursor
  __syncthreads();
  for (int i = t; i < total; i += BSH) {
    int p = stage[i];
    int l = p & (BSH - 1);
    int off = atomicAdd(&cnt[l], 1);
    csr[beg + lofs[l] + off] = p >> 9;
  }
}

// ---- GEMM1 (MFMA): h1[n] = fp16(dis[n] * (x[n] @ W1)); 64 rows/block ----
__global__ void k_gemm1(const float* __restrict__ x, const __half* __restrict__ W1T,
                        const float* __restrict__ dis, __half* __restrict__ out, int N) {
  int t = threadIdx.x;
  int wv = t >> 6, lane = t & 63;
  int m = lane & 15, q = lane >> 4;  // quad
  int row0 = blockIdx.x * 64 + wv * 16;
  int arow = min(row0 + m, N - 1);  // clamp for load safety
  const _Float16* wt = (const _Float16*)W1T;
  f16x8 bf[4][2];
#pragma unroll
  for (int c = 0; c < 4; ++c)
#pragma unroll
    for (int kt = 0; kt < 2; ++kt)
      bf[c][kt] = *(const f16x8*)&wt[(c * 16 + m) * 64 + kt * 32 + q * 8];
  f16x8 a[2];
#pragma unroll
  for (int kt = 0; kt < 2; ++kt) {
    const float4* xp = (const float4*)(x + (size_t)arow * 64 + kt * 32 + q * 8);
    float4 u = xp[0], v = xp[1];
    a[kt][0] = (_Float16)u.x; a[kt][1] = (_Float16)u.y;
    a[kt][2] = (_Float16)u.z; a[kt][3] = (_Float16)u.w;
    a[kt][4] = (_Float16)v.x; a[kt][5] = (_Float16)v.y;
    a[kt][6] = (_Float16)v.z; a[kt][7] = (_Float16)v.w;
  }
  f32x4 acc[4] = {};
#pragma unroll
  for (int kt = 0; kt < 2; ++kt)
#pragma unroll
    for (int c = 0; c < 4; ++c)
      acc[c] = __builtin_amdgcn_mfma_f32_16x16x32_f16(a[kt], bf[c][kt], acc[c], 0, 0, 0);
#pragma unroll
  for (int r = 0; r < 4; ++r) {
    int n = row0 + q * 4 + r;
    if (n < N) {
      float dn = dis[n];
#pragma unroll
      for (int c = 0; c < 4; ++c)
        out[(size_t)n * 64 + c * 16 + m] = __float2half(acc[c][r] * dn);
    }
  }
}

// ---- agg layer 1 + fused GEMM2: 2 nodes/wave (half=32 lanes: 4 subs x 8 fl) ----
__global__ void k_agg1f(const __half* __restrict__ h, const float* __restrict__ dis,
                        const int* __restrict__ rowptr, const int* __restrict__ csr,
                        const float* __restrict__ b1, const __half* __restrict__ W2T,
                        __half* __restrict__ h2, int N) {
  int gt = blockIdx.x * blockDim.x + threadIdx.x;
  int w = gt >> 6;
  int lane = gt & 63;
  int half = lane >> 5;         // node within wave
  int sub = (lane >> 3) & 3;    // 4 edge substreams per node
  int fl = lane & 7;            // feature-octet lane
  int n = w * 2 + half;
  if (n >= N) return;
  const _Float16* hp = (const _Float16*)h;
  float dn = dis[n];
  float4 bu = *(const float4*)(b1 + fl * 8);
  float4 bv = *(const float4*)(b1 + fl * 8 + 4);
  const _Float16* wt = (const _Float16*)W2T;
  // 4 outputs per sub: j = sub*4 + i
  f16x8 wj[4];
#pragma unroll
  for (int i = 0; i < 4; ++i)
    wj[i] = *(const f16x8*)&wt[(sub * 4 + i) * 64 + fl * 8];
  f16x8 acc0 = {}, acc1 = {};
  if (sub == 0)  // self loop (rows pre-scaled by dis)
    acc0 = *(const f16x8*)&hp[(size_t)n * 64 + fl * 8];
  int beg = rowptr[n], end = rowptr[n + 1];
  int e = beg + sub;
  int sA = (e < end) ? csr[e] : -1;
  int sB = (e + 4 < end) ? csr[e + 4] : -1;
  while (sB >= 0) {
    int e2 = e + 8;
    int sC = (e2 < end) ? csr[e2] : -1;
    int sD = (e2 + 4 < end) ? csr[e2 + 4] : -1;
    f16x8 v0 = *(const f16x8*)&hp[(size_t)sA * 64 + fl * 8];
    f16x8 v1 = *(const f16x8*)&hp[(size_t)sB * 64 + fl * 8];
    acc0 += v0;
    acc1 += v1;
    sA = sC; sB = sD; e = e2;
  }
  if (sA >= 0)
    acc0 += *(const f16x8*)&hp[(size_t)sA * 64 + fl * 8];
  f16x8 acc = acc0 + acc1;
  // reduce across the 4 substreams (stay within 32-lane half)
  acc += shfl_xor_f16x8(acc, 8);
  acc += shfl_xor_f16x8(acc, 16);
  // bias + relu in fp32, pack back to fp16
  float bb[8] = {bu.x, bu.y, bu.z, bu.w, bv.x, bv.y, bv.z, bv.w};
  f16x8 hr16;
#pragma unroll
  for (int k = 0; k < 8; ++k)
    hr16[k] = (_Float16)fmaxf(fmaf(dn, (float)acc[k], bb[k]), 0.f);
  // fused gemm2 in packed fp16: outputs j = sub*4 .. sub*4+3
  const f16x2* h2v = (const f16x2*)&hr16;
  float p[4];
#pragma unroll
  for (int i = 0; i < 4; ++i) {
    const f16x2* wv = (const f16x2*)&wj[i];
    f16x2 qq = {};
#pragma unroll
    for (int k = 0; k < 4; ++k) qq += h2v[k] * wv[k];  // v_pk_fma_f16
    float pi = (float)qq[0] + (float)qq[1];
    pi += __shfl_xor(pi, 1);
    pi += __shfl_xor(pi, 2);
    pi += __shfl_xor(pi, 4);
    p[i] = pi;
  }
  if (fl == 0) {
    f16x4 o;
#pragma unroll
    for (int i = 0; i < 4; ++i) o[i] = (_Float16)(p[i] * dn);
    *(f16x4*)((_Float16*)h2 + (size_t)n * 16 + sub * 4) = o;
  }
}

// ---- agg layer 2 + bias + log_softmax: 2 nodes/wave (8 subs x 4 fl per node) ----
__global__ void k_agg2(const __half* __restrict__ h2, const float* __restrict__ dis,
                       const int* __restrict__ rowptr, const int* __restrict__ csr,
                       const float* __restrict__ b2, float* __restrict__ out, int N) {
  int gt = blockIdx.x * blockDim.x + threadIdx.x;
  int w = gt >> 6;
  int lane = gt & 63;
  int half = lane >> 5;
  int sub = (lane >> 2) & 7;  // 8 edge substreams per node
  int fl = lane & 3;          // feature-quad lane
  int n = w * 2 + half;
  if (n >= N) return;
  const _Float16* hp = (const _Float16*)h2;
  f16x4 acc0 = {}, acc1 = {};
  if (sub == 0)  // self loop
    acc0 = *(const f16x4*)&hp[(size_t)n * 16 + fl * 4];
  int beg = rowptr[n], end = rowptr[n + 1];
  int e = beg + sub;
  int sA = (e < end) ? csr[e] : -1;
  int sB = (e + 8 < end) ? csr[e + 8] : -1;
  while (sB >= 0) {
    int e2 = e + 16;
    int sC = (e2 < end) ? csr[e2] : -1;
    int sD = (e2 + 8 < end) ? csr[e2 + 8] : -1;
    f16x4 v0 = *(const f16x4*)&hp[(size_t)sA * 16 + fl * 4];
    f16x4 v1 = *(const f16x4*)&hp[(size_t)sB * 16 + fl * 4];
    acc0 += v0;
    acc1 += v1;
    sA = sC; sB = sD; e = e2;
  }
  if (sA >= 0)
    acc0 += *(const f16x4*)&hp[(size_t)sA * 16 + fl * 4];
  f16x4 acc = acc0 + acc1;
  // reduce across 8 substreams (within half)
  acc += shfl_xor_f16x4(acc, 4);
  acc += shfl_xor_f16x4(acc, 8);
  acc += shfl_xor_f16x4(acc, 16);
  if (sub == 0) {
    float dn = dis[n];
    float4 bb = *(const float4*)(b2 + fl * 4);
    float v0 = fmaf(dn, (float)acc[0], bb.x);
    float v1 = fmaf(dn, (float)acc[1], bb.y);
    float v2 = fmaf(dn, (float)acc[2], bb.z);
    float v3 = fmaf(dn, (float)acc[3], bb.w);
    float m = fmaxf(fmaxf(v0, v1), fmaxf(v2, v3));
    m = fmaxf(m, __shfl_xor(m, 1));
    m = fmaxf(m, __shfl_xor(m, 2));
    float s2 = __expf(v0 - m) + __expf(v1 - m) + __expf(v2 - m) + __expf(v3 - m);
    s2 += __shfl_xor(s2, 1);
    s2 += __shfl_xor(s2, 2);
    float ls = m + __logf(s2);
    float4 o = {v0 - ls, v1 - ls, v2 - ls, v3 - ls};
    *(float4*)(out + (size_t)n * 16 + fl * 4) = o;
  }
}

extern "C" void kernel_launch(void* const* d_in, const int* in_sizes, int n_in,
                              void* d_out, int out_size, void* d_ws, size_t ws_size,
                              hipStream_t stream) {
  const float* x = (const float*)d_in[0];
  const int* ei = (const int*)d_in[1];
  const float* W1 = (const float*)d_in[2];
  const float* b1 = (const float*)d_in[3];
  const float* W2 = (const float*)d_in[4];
  const float* b2 = (const float*)d_in[5];
  float* out = (float*)d_out;

  int N = in_sizes[0] / F1;  // 100000
  int E = in_sizes[1] / 2;   // 1600000
  const int* src = ei;
  const int* dst = ei + E;
  int nb = (N + BSH - 1) >> 9;  // 196 buckets
  int chunk = ((E + NSB - 1) / NSB + 3) & ~3;  // 6252

  char* ws = (char*)d_ws;
  size_t o_w1t   = 0;                                        // 64*64 fp16
  size_t o_w2t   = o_w1t + 64 * 64 * 2;                      // 16*64 fp16
  size_t o_seg   = (o_w2t + 16 * 64 * 2 + 255) & ~(size_t)255;          // NSB*(nb+1) int
  size_t o_dis   = (o_seg + (size_t)NSB * (nb + 1) * 4 + 255) & ~(size_t)255;  // N f32
  size_t o_rowp  = (o_dis + (size_t)N * 4 + 255) & ~(size_t)255;        // N+1 int
  size_t o_tmp   = (o_rowp + (size_t)(N + 1) * 4 + 255) & ~(size_t)255; // NSB*chunk int
  size_t o_csr   = (o_tmp + (size_t)NSB * chunk * 4 + 255) & ~(size_t)255;  // E int
  size_t o_h1    = (o_csr + (size_t)E * 4 + 255) & ~(size_t)255;        // N*64 fp16
  size_t o_h2    = (o_h1 + (size_t)N * 64 * 2 + 255) & ~(size_t)255;    // N*16 fp16

  __half* W1T  = (__half*)(ws + o_w1t);
  __half* W2T  = (__half*)(ws + o_w2t);
  int* segst   = (int*)(ws + o_seg);
  float* dis   = (float*)(ws + o_dis);
  int* rowptr  = (int*)(ws + o_rowp);
  int* tmp     = (int*)(ws + o_tmp);
  int* csr     = (int*)(ws + o_csr);
  __half* h1   = (__half*)(ws + o_h1);
  __half* h2   = (__half*)(ws + o_h2);

  k_scatterL<<<NSB + 1, SBD, 0, stream>>>(src, dst, tmp, segst, E, nb, chunk,
                                          W1, W2, W1T, W2T);
  k_csr<<<nb, BSH, 0, stream>>>(tmp, segst, csr, rowptr, dis, N, nb, chunk);

  int gb = (N + 63) / 64;  // 1563
  k_gemm1<<<gb, 256, 0, stream>>>(x, W1T, dis, h1, N);
  int aw = (N + 1) / 2;  // waves for 2-node-per-wave agg kernels
  k_agg1f<<<((size_t)aw * 64 + 255) / 256, 256, 0, stream>>>(h1, dis, rowptr, csr, b1, W2T, h2, N);
  k_agg2<<<((size_t)aw * 64 + 255) / 256, 256, 0, stream>>>(h2, dis, rowptr, csr, b2, out, N);
}